// Round 1
// baseline (595.461 us; speedup 1.0000x reference)
//
#include <hip/hip_runtime.h>
#include <stdint.h>

// Problem constants (match reference)
#define N_PRIORS 2097152
#define KTOP 512
#define NBINS 2048
#define SEL_CAP 4096

// ws layout (bytes):
//   0:  u32 cnt[4]   {M, M2, B, pad}
//   16: u32 hist[2048]               (ends 8208)
//   8224: u64 sel[4096]              (32 KB, ends 40992)
//   40992: u64 cand[ccap]            (rest of ws)

__device__ __forceinline__ uint64_t pack_key(float s, int idx) {
    // descending score, ascending index tie-break (== stable top_k)
    return ((uint64_t)__float_as_uint(s) << 32) | (uint32_t)(~idx);
}

__global__ void pass1_score(const float4* __restrict__ conf4,
                            uint32_t* __restrict__ cnt,
                            uint32_t* __restrict__ hist,
                            uint64_t* __restrict__ cand,
                            uint32_t ccap) {
    #pragma clang fp contract(off)
    int gid = blockIdx.x * blockDim.x + threadIdx.x;  // handles elements 2*gid, 2*gid+1
    float4 c = conf4[gid];
    #pragma unroll
    for (int e = 0; e < 2; ++e) {
        float c0 = e ? c.z : c.x;
        float c1 = e ? c.w : c.y;
        float m  = fmaxf(c0, c1);
        float e0 = expf(c0 - m);    // one of these is exp(0)=1 exactly
        float e1 = expf(c1 - m);
        float s  = e1 / (e0 + e1);  // softmax[:,1]
        if (s > 0.9f) {
            int b = (int)((s - 0.9f) * 20480.0f);   // 2048 bins over (0.9, 1.0]
            b = b > (NBINS - 1) ? (NBINS - 1) : b;
            atomicAdd(&hist[b], 1u);
            uint32_t pos = atomicAdd(&cnt[0], 1u);  // wave-aggregated by compiler
            if (pos < ccap) cand[pos] = pack_key(s, 2 * gid + e);
        }
    }
}

__global__ void pass2_findB(const uint32_t* __restrict__ hist,
                            uint32_t* __restrict__ cnt) {
    __shared__ int suf[NBINS];
    __shared__ int bmax;
    int tid = threadIdx.x;  // 256 threads
    for (int b = tid; b < NBINS; b += 256) suf[b] = (int)hist[b];
    if (tid == 0) bmax = 0;
    __syncthreads();
    // Hillis-Steele inclusive suffix scan
    for (int off = 1; off < NBINS; off <<= 1) {
        int v[8];
        #pragma unroll
        for (int e = 0; e < 8; ++e) {
            int b = tid + 256 * e;
            v[e] = suf[b] + ((b + off < NBINS) ? suf[b + off] : 0);
        }
        __syncthreads();
        #pragma unroll
        for (int e = 0; e < 8; ++e) suf[tid + 256 * e] = v[e];
        __syncthreads();
    }
    // B = max b with suffix(b) >= KTOP  (0 if fewer than KTOP candidates total)
    #pragma unroll
    for (int e = 0; e < 8; ++e) {
        int b = tid + 256 * e;
        if (suf[b] >= KTOP) atomicMax(&bmax, b);
    }
    __syncthreads();
    if (tid == 0) cnt[2] = (uint32_t)bmax;
}

__global__ void pass3_compact(const uint64_t* __restrict__ cand,
                              uint32_t* __restrict__ cnt,
                              uint64_t* __restrict__ sel,
                              uint32_t ccap) {
    uint32_t M = cnt[0]; if (M > ccap) M = ccap;
    int B = (int)cnt[2];
    uint32_t stride = gridDim.x * blockDim.x;
    for (uint32_t p = blockIdx.x * blockDim.x + threadIdx.x; p < M; p += stride) {
        uint64_t key = cand[p];
        float s = __uint_as_float((uint32_t)(key >> 32));
        int b = (int)((s - 0.9f) * 20480.0f);   // identical binning to pass1
        b = b > (NBINS - 1) ? (NBINS - 1) : b;
        if (b >= B) {
            uint32_t pos = atomicAdd(&cnt[1], 1u);
            if (pos < SEL_CAP) sel[pos] = key;
        }
    }
}

__launch_bounds__(1024)
__global__ void pass4_nms(const float4* __restrict__ loc,
                          const float4* __restrict__ priors,
                          const uint32_t* __restrict__ cnt,
                          const uint64_t* __restrict__ sel,
                          float* __restrict__ out) {
    #pragma clang fp contract(off)
    __shared__ uint64_t keys[SEL_CAP];                       // 32 KB
    __shared__ float bx1[KTOP], by1[KTOP], bx2[KTOP], by2[KTOP];
    __shared__ float sarea[KTOP], ssc[KTOP];
    __shared__ int keep[KTOP];
    int tid = threadIdx.x;  // 1024 threads

    int n = (int)cnt[1]; if (n > SEL_CAP) n = SEL_CAP;
    int P = 1024; while (P < n) P <<= 1;
    for (int t = tid; t < P; t += 1024) keys[t] = (t < n) ? sel[t] : 0ull;
    __syncthreads();

    // bitonic sort, descending (key 0 padding sinks to the end)
    for (int k = 2; k <= P; k <<= 1) {
        for (int j = k >> 1; j > 0; j >>= 1) {
            for (int t = tid; t < P; t += 1024) {
                int ixj = t ^ j;
                if (ixj > t) {
                    uint64_t a = keys[t], b = keys[ixj];
                    bool sw = ((t & k) == 0) ? (a < b) : (a > b);
                    if (sw) { keys[t] = b; keys[ixj] = a; }
                }
            }
            __syncthreads();
        }
    }

    // gather + decode top-512 (exact numpy op order, no fma contraction)
    if (tid < KTOP) {
        uint64_t key = keys[tid];
        if (key != 0ull) {
            float s  = __uint_as_float((uint32_t)(key >> 32));
            int idx  = (int)(~(uint32_t)key);
            float4 l = loc[idx];
            float4 p = priors[idx];
            float cx = p.x + (l.x * 0.1f) * p.z;
            float cy = p.y + (l.y * 0.1f) * p.w;
            float w  = p.z * expf(l.z * 0.2f);
            float h  = p.w * expf(l.w * 0.2f);
            float x1 = cx - w * 0.5f;
            float y1 = cy - h * 0.5f;
            float x2 = x1 + w;
            float y2 = y1 + h;
            x1 *= 2048.0f; y1 *= 2048.0f; x2 *= 2048.0f; y2 *= 2048.0f;
            bx1[tid] = x1; by1[tid] = y1; bx2[tid] = x2; by2[tid] = y2;
            sarea[tid] = (x2 - x1 + 1.0f) * (y2 - y1 + 1.0f);
            ssc[tid] = s;
            keep[tid] = 1;
        } else {
            bx1[tid] = 0.f; by1[tid] = 0.f; bx2[tid] = 0.f; by2[tid] = 0.f;
            sarea[tid] = 1.f; ssc[tid] = 0.f; keep[tid] = 0;
        }
    }
    __syncthreads();

    // greedy NMS; barrier only on iterations that suppress (~#kept, not 512)
    volatile int* vkeep = keep;
    for (int i = 0; i < KTOP; ++i) {
        if (vkeep[i]) {                 // wave-uniform: single LDS location
            if (tid > i && tid < KTOP) {
                float xx1 = fmaxf(bx1[i], bx1[tid]);
                float yy1 = fmaxf(by1[i], by1[tid]);
                float xx2 = fminf(bx2[i], bx2[tid]);
                float yy2 = fminf(by2[i], by2[tid]);
                float ww = fmaxf(xx2 - xx1 + 1.0f, 0.0f);
                float hh = fmaxf(yy2 - yy1 + 1.0f, 0.0f);
                float inter = ww * hh;
                float iou = inter / (sarea[i] + sarea[tid] - inter);
                if (iou > 0.4f) keep[tid] = 0;
            }
            __syncthreads();
        }
    }

    // epilogue: [512,5] = [x1,y1,x2,y2]/2048 (exact pow2), score; zeros if !keep
    if (tid < KTOP) {
        const float inv = 1.0f / 2048.0f;  // exact
        float* o = out + tid * 5;
        if (keep[tid]) {
            o[0] = bx1[tid] * inv;
            o[1] = by1[tid] * inv;
            o[2] = bx2[tid] * inv;
            o[3] = by2[tid] * inv;
            o[4] = ssc[tid];
        } else {
            o[0] = 0.f; o[1] = 0.f; o[2] = 0.f; o[3] = 0.f; o[4] = 0.f;
        }
    }
}

extern "C" void kernel_launch(void* const* d_in, const int* in_sizes, int n_in,
                              void* d_out, int out_size, void* d_ws, size_t ws_size,
                              hipStream_t stream) {
    const float* loc    = (const float*)d_in[0];   // [1,N,4]
    const float* conf   = (const float*)d_in[1];   // [1,N,2]
    const float* priors = (const float*)d_in[2];   // [N,4]
    float* out = (float*)d_out;                    // [512,5]

    uint8_t* ws = (uint8_t*)d_ws;
    uint32_t* cnt  = (uint32_t*)ws;
    uint32_t* hist = (uint32_t*)(ws + 16);
    uint64_t* sel  = (uint64_t*)(ws + 8224);
    uint64_t* cand = (uint64_t*)(ws + 40992);
    uint32_t ccap = (ws_size > 40992) ? (uint32_t)((ws_size - 40992) / 8) : 0u;
    if (ccap > N_PRIORS) ccap = N_PRIORS;

    hipMemsetAsync(d_ws, 0, 8208, stream);  // counters + histogram

    // pass1: N/2 float4 loads, 2 elements/thread
    pass1_score<<<N_PRIORS / 512, 256, 0, stream>>>((const float4*)conf, cnt, hist, cand, ccap);
    pass2_findB<<<1, 256, 0, stream>>>(hist, cnt);
    pass3_compact<<<512, 256, 0, stream>>>(cand, cnt, sel, ccap);
    pass4_nms<<<1, 1024, 0, stream>>>((const float4*)loc, (const float4*)priors, cnt, sel, out);
}

// Round 2
// 313.326 us; speedup vs baseline: 1.9004x; 1.9004x over previous
//
#include <hip/hip_runtime.h>
#include <stdint.h>

// Problem constants (match reference)
#define N_PRIORS 2097152
#define KTOP 512
#define NBINS 2048
#define SEL_CAP 4096

// ws layout (bytes):
//   0:    u32 cnt[4]   {unused, M2(sel count), B, pad}
//   16:   u32 hist[2048]             (ends 8208)
//   8224: u64 sel[4096]              (32 KB, ends 40992)

__device__ __forceinline__ uint64_t pack_key(float s, int idx) {
    // descending score, ascending index tie-break (== stable top_k)
    return ((uint64_t)__float_as_uint(s) << 32) | (uint32_t)(~idx);
}

__device__ __forceinline__ float score_of(float c0, float c1) {
    #pragma clang fp contract(off)
    float m  = fmaxf(c0, c1);
    float e0 = expf(c0 - m);
    float e1 = expf(c1 - m);
    return e1 / (e0 + e1);
}

__device__ __forceinline__ int bin_of(float s) {
    #pragma clang fp contract(off)
    int b = (int)((s - 0.9f) * 20480.0f);   // 2048 bins over (0.9, 1.0]
    return b > (NBINS - 1) ? (NBINS - 1) : b;
}

// Pass 1: histogram only — no global compaction counter (that was the 385 us).
__global__ void pass1_hist(const float4* __restrict__ conf4,
                           uint32_t* __restrict__ hist) {
    #pragma clang fp contract(off)
    int gid = blockIdx.x * blockDim.x + threadIdx.x;  // elements 2*gid, 2*gid+1
    float4 c = conf4[gid];
    float s0 = score_of(c.x, c.y);
    float s1 = score_of(c.z, c.w);
    if (s0 > 0.9f) atomicAdd(&hist[bin_of(s0)], 1u);
    if (s1 > 0.9f) atomicAdd(&hist[bin_of(s1)], 1u);
}

__global__ void pass2_findB(const uint32_t* __restrict__ hist,
                            uint32_t* __restrict__ cnt) {
    __shared__ int suf[NBINS];
    __shared__ int bmax;
    int tid = threadIdx.x;  // 256 threads
    for (int b = tid; b < NBINS; b += 256) suf[b] = (int)hist[b];
    if (tid == 0) bmax = 0;
    __syncthreads();
    // Hillis-Steele inclusive suffix scan
    for (int off = 1; off < NBINS; off <<= 1) {
        int v[8];
        #pragma unroll
        for (int e = 0; e < 8; ++e) {
            int b = tid + 256 * e;
            v[e] = suf[b] + ((b + off < NBINS) ? suf[b + off] : 0);
        }
        __syncthreads();
        #pragma unroll
        for (int e = 0; e < 8; ++e) suf[tid + 256 * e] = v[e];
        __syncthreads();
    }
    // B = max b with suffix(b) >= KTOP  (0 if fewer than KTOP candidates total)
    #pragma unroll
    for (int e = 0; e < 8; ++e) {
        int b = tid + 256 * e;
        if (suf[b] >= KTOP) atomicMax(&bmax, b);
    }
    __syncthreads();
    if (tid == 0) cnt[2] = (uint32_t)bmax;
}

// Pass 3: re-read conf (L3-warm), select bin >= B (~520 winners -> ~500 atomics).
__global__ void pass3_select(const float4* __restrict__ conf4,
                             uint32_t* __restrict__ cnt,
                             uint64_t* __restrict__ sel) {
    #pragma clang fp contract(off)
    int gid = blockIdx.x * blockDim.x + threadIdx.x;
    int B = (int)cnt[2];
    float4 c = conf4[gid];
    float s0 = score_of(c.x, c.y);
    float s1 = score_of(c.z, c.w);
    if (s0 > 0.9f && bin_of(s0) >= B) {
        uint32_t pos = atomicAdd(&cnt[1], 1u);
        if (pos < SEL_CAP) sel[pos] = pack_key(s0, 2 * gid);
    }
    if (s1 > 0.9f && bin_of(s1) >= B) {
        uint32_t pos = atomicAdd(&cnt[1], 1u);
        if (pos < SEL_CAP) sel[pos] = pack_key(s1, 2 * gid + 1);
    }
}

__launch_bounds__(1024)
__global__ void pass4_nms(const float4* __restrict__ loc,
                          const float4* __restrict__ priors,
                          const uint32_t* __restrict__ cnt,
                          const uint64_t* __restrict__ sel,
                          float* __restrict__ out) {
    #pragma clang fp contract(off)
    __shared__ uint64_t keys[SEL_CAP];                       // 32 KB
    __shared__ float bx1[KTOP], by1[KTOP], bx2[KTOP], by2[KTOP];
    __shared__ float sarea[KTOP], ssc[KTOP];
    __shared__ int keep[KTOP];
    int tid = threadIdx.x;  // 1024 threads

    int n = (int)cnt[1]; if (n > SEL_CAP) n = SEL_CAP;
    int P = 1024; while (P < n) P <<= 1;
    for (int t = tid; t < P; t += 1024) keys[t] = (t < n) ? sel[t] : 0ull;
    __syncthreads();

    // bitonic sort, descending (key 0 padding sinks to the end)
    for (int k = 2; k <= P; k <<= 1) {
        for (int j = k >> 1; j > 0; j >>= 1) {
            for (int t = tid; t < P; t += 1024) {
                int ixj = t ^ j;
                if (ixj > t) {
                    uint64_t a = keys[t], b = keys[ixj];
                    bool sw = ((t & k) == 0) ? (a < b) : (a > b);
                    if (sw) { keys[t] = b; keys[ixj] = a; }
                }
            }
            __syncthreads();
        }
    }

    // gather + decode top-512 (exact numpy op order, no fma contraction)
    if (tid < KTOP) {
        uint64_t key = keys[tid];
        if (key != 0ull) {
            float s  = __uint_as_float((uint32_t)(key >> 32));
            int idx  = (int)(~(uint32_t)key);
            float4 l = loc[idx];
            float4 p = priors[idx];
            float cx = p.x + (l.x * 0.1f) * p.z;
            float cy = p.y + (l.y * 0.1f) * p.w;
            float w  = p.z * expf(l.z * 0.2f);
            float h  = p.w * expf(l.w * 0.2f);
            float x1 = cx - w * 0.5f;
            float y1 = cy - h * 0.5f;
            float x2 = x1 + w;
            float y2 = y1 + h;
            x1 *= 2048.0f; y1 *= 2048.0f; x2 *= 2048.0f; y2 *= 2048.0f;
            bx1[tid] = x1; by1[tid] = y1; bx2[tid] = x2; by2[tid] = y2;
            sarea[tid] = (x2 - x1 + 1.0f) * (y2 - y1 + 1.0f);
            ssc[tid] = s;
            keep[tid] = 1;
        } else {
            bx1[tid] = 0.f; by1[tid] = 0.f; bx2[tid] = 0.f; by2[tid] = 0.f;
            sarea[tid] = 1.f; ssc[tid] = 0.f; keep[tid] = 0;
        }
    }
    __syncthreads();

    // greedy NMS in ONE wave, register-resident: lane L owns candidates
    // {s*64+L : s in 0..7}. Broadcast suppressor via shuffle; no barriers,
    // no volatile-LDS serial chain. Dead iterations cost 1 shuffle.
    if (tid < 64) {
        float rx1[8], ry1[8], rx2[8], ry2[8], rar[8];
        int rkeep[8];
        #pragma unroll
        for (int s = 0; s < 8; ++s) {
            int c = s * 64 + tid;
            rx1[s] = bx1[c]; ry1[s] = by1[c]; rx2[s] = bx2[c]; ry2[s] = by2[c];
            rar[s] = sarea[c]; rkeep[s] = keep[c];
        }
        #pragma unroll
        for (int slot = 0; slot < 8; ++slot) {       // slot = i >> 6 (compile-time)
            for (int i2 = 0; i2 < 64; ++i2) {
                int i = slot * 64 + i2;
                int ki = __shfl(rkeep[slot], i2);
                if (ki) {
                    float ix1 = __shfl(rx1[slot], i2);
                    float iy1 = __shfl(ry1[slot], i2);
                    float ix2 = __shfl(rx2[slot], i2);
                    float iy2 = __shfl(ry2[slot], i2);
                    float iar = __shfl(rar[slot], i2);
                    #pragma unroll
                    for (int s = 0; s < 8; ++s) {
                        int c = s * 64 + tid;
                        if (c > i && rkeep[s]) {
                            float xx1 = fmaxf(ix1, rx1[s]);
                            float yy1 = fmaxf(iy1, ry1[s]);
                            float xx2 = fminf(ix2, rx2[s]);
                            float yy2 = fminf(iy2, ry2[s]);
                            float ww = fmaxf(xx2 - xx1 + 1.0f, 0.0f);
                            float hh = fmaxf(yy2 - yy1 + 1.0f, 0.0f);
                            float inter = ww * hh;
                            float iou = inter / (iar + rar[s] - inter);
                            if (iou > 0.4f) rkeep[s] = 0;
                        }
                    }
                }
            }
        }
        #pragma unroll
        for (int s = 0; s < 8; ++s) keep[s * 64 + tid] = rkeep[s];
    }
    __syncthreads();

    // epilogue: [512,5] = [x1,y1,x2,y2]/2048 (exact pow2), score; zeros if !keep
    if (tid < KTOP) {
        const float inv = 1.0f / 2048.0f;  // exact
        float* o = out + tid * 5;
        if (keep[tid]) {
            o[0] = bx1[tid] * inv;
            o[1] = by1[tid] * inv;
            o[2] = bx2[tid] * inv;
            o[3] = by2[tid] * inv;
            o[4] = ssc[tid];
        } else {
            o[0] = 0.f; o[1] = 0.f; o[2] = 0.f; o[3] = 0.f; o[4] = 0.f;
        }
    }
}

extern "C" void kernel_launch(void* const* d_in, const int* in_sizes, int n_in,
                              void* d_out, int out_size, void* d_ws, size_t ws_size,
                              hipStream_t stream) {
    const float* loc    = (const float*)d_in[0];   // [1,N,4]
    const float* conf   = (const float*)d_in[1];   // [1,N,2]
    const float* priors = (const float*)d_in[2];   // [N,4]
    float* out = (float*)d_out;                    // [512,5]

    uint8_t* ws = (uint8_t*)d_ws;
    uint32_t* cnt  = (uint32_t*)ws;
    uint32_t* hist = (uint32_t*)(ws + 16);
    uint64_t* sel  = (uint64_t*)(ws + 8224);

    hipMemsetAsync(d_ws, 0, 8208, stream);  // counters + histogram

    pass1_hist<<<N_PRIORS / 512, 256, 0, stream>>>((const float4*)conf, hist);
    pass2_findB<<<1, 256, 0, stream>>>(hist, cnt);
    pass3_select<<<N_PRIORS / 512, 256, 0, stream>>>((const float4*)conf, cnt, sel);
    pass4_nms<<<1, 1024, 0, stream>>>((const float4*)loc, (const float4*)priors, cnt, sel, out);
}

// Round 3
// 222.856 us; speedup vs baseline: 2.6720x; 1.4060x over previous
//
#include <hip/hip_runtime.h>
#include <stdint.h>

// Problem constants (match reference)
#define N_PRIORS 2097152
#define KTOP 512
#define NBINS 2048
#define SEL_CAP 4096
// scatter adjacent (hot) bins across different 64B lines to avoid per-line
// atomic serialization; 73 is odd -> bijective mod 2048
#define HSLOT(b) (((b) * 73) & (NBINS - 1))

// ws layout (bytes):
//   0:    u32 cnt[4]   {unused, M2(sel count), B, pad}
//   16:   u32 hist[2048]             (ends 8208)
//   8224: u64 sel[4096]              (32 KB, ends 40992)

__device__ __forceinline__ uint64_t pack_key(float s, int idx) {
    // descending score, ascending index tie-break (== stable top_k)
    return ((uint64_t)__float_as_uint(s) << 32) | (uint32_t)(~idx);
}

__device__ __forceinline__ float score_of(float c0, float c1) {
    #pragma clang fp contract(off)
    float m  = fmaxf(c0, c1);
    float e0 = expf(c0 - m);
    float e1 = expf(c1 - m);
    return e1 / (e0 + e1);
}

__device__ __forceinline__ int bin_of(float s) {
    #pragma clang fp contract(off)
    int b = (int)((s - 0.9f) * 20480.0f);   // 2048 bins over (0.9, 1.0]
    return b > (NBINS - 1) ? (NBINS - 1) : b;
}

// Pass 1: histogram only — scattered atomics, no global compaction counter.
__global__ void pass1_hist(const float4* __restrict__ conf4,
                           uint32_t* __restrict__ hist) {
    #pragma clang fp contract(off)
    int gid = blockIdx.x * blockDim.x + threadIdx.x;  // elements 2*gid, 2*gid+1
    float4 c = conf4[gid];
    float s0 = score_of(c.x, c.y);
    float s1 = score_of(c.z, c.w);
    if (s0 > 0.9f) atomicAdd(&hist[HSLOT(bin_of(s0))], 1u);
    if (s1 > 0.9f) atomicAdd(&hist[HSLOT(bin_of(s1))], 1u);
}

__global__ void pass2_findB(const uint32_t* __restrict__ hist,
                            uint32_t* __restrict__ cnt) {
    __shared__ int suf[NBINS];
    __shared__ int bmax;
    int tid = threadIdx.x;  // 256 threads
    for (int b = tid; b < NBINS; b += 256) suf[b] = (int)hist[HSLOT(b)];
    if (tid == 0) bmax = 0;
    __syncthreads();
    // Hillis-Steele inclusive suffix scan
    for (int off = 1; off < NBINS; off <<= 1) {
        int v[8];
        #pragma unroll
        for (int e = 0; e < 8; ++e) {
            int b = tid + 256 * e;
            v[e] = suf[b] + ((b + off < NBINS) ? suf[b + off] : 0);
        }
        __syncthreads();
        #pragma unroll
        for (int e = 0; e < 8; ++e) suf[tid + 256 * e] = v[e];
        __syncthreads();
    }
    // B = max b with suffix(b) >= KTOP  (0 if fewer than KTOP candidates total)
    #pragma unroll
    for (int e = 0; e < 8; ++e) {
        int b = tid + 256 * e;
        if (suf[b] >= KTOP) atomicMax(&bmax, b);
    }
    __syncthreads();
    if (tid == 0) cnt[2] = (uint32_t)bmax;
}

// Pass 3: re-read conf (L3-warm), select bin >= B (~520 winners -> ~520 atomics).
__global__ void pass3_select(const float4* __restrict__ conf4,
                             uint32_t* __restrict__ cnt,
                             uint64_t* __restrict__ sel) {
    #pragma clang fp contract(off)
    int gid = blockIdx.x * blockDim.x + threadIdx.x;
    int B = (int)cnt[2];
    float4 c = conf4[gid];
    float s0 = score_of(c.x, c.y);
    float s1 = score_of(c.z, c.w);
    if (s0 > 0.9f && bin_of(s0) >= B) {
        uint32_t pos = atomicAdd(&cnt[1], 1u);
        if (pos < SEL_CAP) sel[pos] = pack_key(s0, 2 * gid);
    }
    if (s1 > 0.9f && bin_of(s1) >= B) {
        uint32_t pos = atomicAdd(&cnt[1], 1u);
        if (pos < SEL_CAP) sel[pos] = pack_key(s1, 2 * gid + 1);
    }
}

__launch_bounds__(1024)
__global__ void pass4_nms(const float4* __restrict__ loc,
                          const float4* __restrict__ priors,
                          const uint32_t* __restrict__ cnt,
                          const uint64_t* __restrict__ sel,
                          float* __restrict__ out) {
    #pragma clang fp contract(off)
    __shared__ uint64_t keys[SEL_CAP];     // 32 KB; reused as supB after decode
    __shared__ float4 bpk[KTOP];           // pixel boxes x1,y1,x2,y2 (8 KB)
    __shared__ float sar[KTOP], ssc[KTOP];
    __shared__ uint32_t valid32[16], rowany32[16];
    __shared__ uint64_t keepw[8];
    int tid = threadIdx.x;  // 1024 threads

    if (tid < 16) { valid32[tid] = 0u; rowany32[tid] = 0u; }

    int n = (int)cnt[1]; if (n > SEL_CAP) n = SEL_CAP;
    int P = 1024; while (P < n) P <<= 1;
    for (int t = tid; t < P; t += 1024) keys[t] = (t < n) ? sel[t] : 0ull;
    __syncthreads();

    // bitonic sort, descending (key 0 padding sinks to the end)
    for (int k = 2; k <= P; k <<= 1) {
        for (int j = k >> 1; j > 0; j >>= 1) {
            for (int t = tid; t < P; t += 1024) {
                int ixj = t ^ j;
                if (ixj > t) {
                    uint64_t a = keys[t], b = keys[ixj];
                    bool sw = ((t & k) == 0) ? (a < b) : (a > b);
                    if (sw) { keys[t] = b; keys[ixj] = a; }
                }
            }
            __syncthreads();
        }
    }

    // gather + decode top-512 (exact numpy op order, no fma contraction)
    if (tid < KTOP) {
        uint64_t key = keys[tid];
        float4 bb; float area, sc;
        if (key != 0ull) {
            sc = __uint_as_float((uint32_t)(key >> 32));
            int idx  = (int)(~(uint32_t)key);
            float4 l = loc[idx];
            float4 p = priors[idx];
            float cx = p.x + (l.x * 0.1f) * p.z;
            float cy = p.y + (l.y * 0.1f) * p.w;
            float w  = p.z * expf(l.z * 0.2f);
            float h  = p.w * expf(l.w * 0.2f);
            float x1 = cx - w * 0.5f;
            float y1 = cy - h * 0.5f;
            float x2 = x1 + w;
            float y2 = y1 + h;
            x1 *= 2048.0f; y1 *= 2048.0f; x2 *= 2048.0f; y2 *= 2048.0f;
            bb = make_float4(x1, y1, x2, y2);
            area = (x2 - x1 + 1.0f) * (y2 - y1 + 1.0f);
            atomicOr(&valid32[tid >> 5], 1u << (tid & 31));
        } else {
            bb = make_float4(0.f, 0.f, 0.f, 0.f); area = 1.f; sc = 0.f;
        }
        bpk[tid] = bb; sar[tid] = area; ssc[tid] = sc;
    }
    __syncthreads();   // keys dead from here; alias as suppression matrix

    uint8_t* supB = (uint8_t*)keys;  // supB[r*64 + L] = 8-bit mask, cols 8L..8L+7

    // suppression matrix: wave wv sweeps rows [32wv, 32wv+32); lane owns 8
    // register-resident col boxes (conflict-free b128 LDS loads, row broadcast).
    {
        int lane = tid & 63, wv = tid >> 6;
        float4 cb[8]; float car[8];
        #pragma unroll
        for (int c = 0; c < 8; ++c) {
            int j = lane * 8 + c;
            cb[c] = bpk[j];
            // identical formula+inputs as decode -> bit-identical to sar[j]
            car[c] = (cb[c].z - cb[c].x + 1.0f) * (cb[c].w - cb[c].y + 1.0f);
        }
        for (int rr = 0; rr < 32; ++rr) {
            int r = wv * 32 + rr;
            float4 rb = bpk[r];     // broadcast
            float ra = sar[r];      // broadcast
            uint32_t m8 = 0u;
            #pragma unroll
            for (int c = 0; c < 8; ++c) {
                int j = lane * 8 + c;
                float xx1 = fmaxf(rb.x, cb[c].x);
                float yy1 = fmaxf(rb.y, cb[c].y);
                float xx2 = fminf(rb.z, cb[c].z);
                float yy2 = fminf(rb.w, cb[c].w);
                float ww = fmaxf(xx2 - xx1 + 1.0f, 0.0f);
                float hh = fmaxf(yy2 - yy1 + 1.0f, 0.0f);
                float inter = ww * hh;
                float iou = inter / (ra + car[c] - inter);
                if (iou > 0.4f && j > r) m8 |= (1u << c);
            }
            supB[r * 64 + lane] = (uint8_t)m8;
            if (m8) atomicOr(&rowany32[r >> 5], 1u << (r & 31));
        }
    }
    __syncthreads();

    // greedy scan: keep mask in registers of one thread; only rows that are
    // still kept AND suppress something cost anything (O(kept), not O(512)).
    if (tid == 0) {
        const uint64_t* sup64 = (const uint64_t*)supB;
        uint64_t kp[8];
        #pragma unroll
        for (int c = 0; c < 8; ++c)
            kp[c] = (uint64_t)valid32[2 * c] | ((uint64_t)valid32[2 * c + 1] << 32);
        for (int c = 0; c < 8; ++c) {
            uint64_t ra = (uint64_t)rowany32[2 * c] | ((uint64_t)rowany32[2 * c + 1] << 32);
            uint64_t m = kp[c] & ra;
            while (m) {
                int b = __builtin_ctzll(m);
                int i = c * 64 + b;
                #pragma unroll
                for (int w = 0; w < 8; ++w) kp[w] &= ~sup64[i * 8 + w];
                uint64_t above = (b == 63) ? 0ull : (~0ull << (b + 1));
                m = kp[c] & ra & above;   // row i has no self-bit (j > i only)
            }
        }
        #pragma unroll
        for (int c = 0; c < 8; ++c) keepw[c] = kp[c];
    }
    __syncthreads();

    // epilogue: [512,5] = [x1,y1,x2,y2]/2048 (exact pow2), score; zeros if !keep
    if (tid < KTOP) {
        const float inv = 1.0f / 2048.0f;  // exact
        int kb = (int)((keepw[tid >> 6] >> (tid & 63)) & 1ull);
        float4 bb = bpk[tid];
        float* o = out + tid * 5;
        if (kb) {
            o[0] = bb.x * inv;
            o[1] = bb.y * inv;
            o[2] = bb.z * inv;
            o[3] = bb.w * inv;
            o[4] = ssc[tid];
        } else {
            o[0] = 0.f; o[1] = 0.f; o[2] = 0.f; o[3] = 0.f; o[4] = 0.f;
        }
    }
}

extern "C" void kernel_launch(void* const* d_in, const int* in_sizes, int n_in,
                              void* d_out, int out_size, void* d_ws, size_t ws_size,
                              hipStream_t stream) {
    const float* loc    = (const float*)d_in[0];   // [1,N,4]
    const float* conf   = (const float*)d_in[1];   // [1,N,2]
    const float* priors = (const float*)d_in[2];   // [N,4]
    float* out = (float*)d_out;                    // [512,5]

    uint8_t* ws = (uint8_t*)d_ws;
    uint32_t* cnt  = (uint32_t*)ws;
    uint32_t* hist = (uint32_t*)(ws + 16);
    uint64_t* sel  = (uint64_t*)(ws + 8224);

    hipMemsetAsync(d_ws, 0, 8208, stream);  // counters + histogram

    pass1_hist<<<N_PRIORS / 512, 256, 0, stream>>>((const float4*)conf, hist);
    pass2_findB<<<1, 256, 0, stream>>>(hist, cnt);
    pass3_select<<<N_PRIORS / 512, 256, 0, stream>>>((const float4*)conf, cnt, sel);
    pass4_nms<<<1, 1024, 0, stream>>>((const float4*)loc, (const float4*)priors, cnt, sel, out);
}